// Round 1
// baseline (114.908 us; speedup 1.0000x reference)
//
#include <hip/hip_runtime.h>

// GAE over T steps: reverse affine scan + standardize.
// adv_k = delta_k + c_k * adv_{k+1};  delta_k = r_k + g*V_{k+1}*nd_k - V_k;  c_k = g*l*nd_k
// Affine f(x) = D + C*x; compose(left,right) = (Dl + Cl*Dr, Cl*Cr), left = lower index.

#define GAMMA_F 0.99f
#define GL_F 0.9405f            // 0.99 * 0.95
#define EPS_F 1e-8f

constexpr int NT = 256;          // threads per block
constexpr int SEG = 16;          // elements per thread (one 64B line per array)
constexpr int CHUNK = NT * SEG;  // 4096

// Load this thread's contiguous 16-element segment and form delta/cont in registers.
__device__ __forceinline__ void load_seg(const float* __restrict__ r,
                                         const float* __restrict__ v,
                                         const int* __restrict__ dn,
                                         int s, float* delta, float* cont) {
    float4 rr[4], vv[4];
    int4 dd[4];
#pragma unroll
    for (int i = 0; i < 4; ++i) {
        rr[i] = ((const float4*)(r + s))[i];
        vv[i] = ((const float4*)(v + s))[i];
        dd[i] = ((const int4*)(dn + s))[i];
    }
    float va[SEG + 1];
#pragma unroll
    for (int i = 0; i < 4; ++i) {
        va[4 * i + 0] = vv[i].x; va[4 * i + 1] = vv[i].y;
        va[4 * i + 2] = vv[i].z; va[4 * i + 3] = vv[i].w;
    }
    va[SEG] = v[s + SEG];
#pragma unroll
    for (int i = 0; i < 4; ++i) {
        float r0[4] = {rr[i].x, rr[i].y, rr[i].z, rr[i].w};
        int   d0[4] = {dd[i].x, dd[i].y, dd[i].z, dd[i].w};
#pragma unroll
        for (int j = 0; j < 4; ++j) {
            int k = 4 * i + j;
            float nd = 1.0f - (float)d0[j];
            delta[k] = r0[j] + GAMMA_F * va[k + 1] * nd - va[k];
            cont[k]  = GL_F * nd;
        }
    }
}

// Inclusive reverse scan of per-thread affines: after call, (Ds[t],Cs[t]) = A_t∘A_{t+1}∘...∘A_{NT-1}
__device__ __forceinline__ void block_rscan(float D, float C, float* Ds, float* Cs, int t) {
    Ds[t] = D; Cs[t] = C;
    __syncthreads();
    for (int off = 1; off < NT; off <<= 1) {
        float d2 = 0.f, c2 = 0.f;
        bool act = (t + off) < NT;
        if (act) { d2 = Ds[t + off]; c2 = Cs[t + off]; }
        __syncthreads();
        if (act) { float a = Ds[t] + Cs[t] * d2; float b = Cs[t] * c2; Ds[t] = a; Cs[t] = b; }
        __syncthreads();
    }
}

// Pass 1: per-chunk composed affine
__global__ __launch_bounds__(NT) void k_chunk_affine(const float* __restrict__ r,
                                                     const float* __restrict__ v,
                                                     const int* __restrict__ dn,
                                                     float2* __restrict__ aff) {
    const int t = threadIdx.x;
    const int s = blockIdx.x * CHUNK + t * SEG;
    float delta[SEG], cont[SEG];
    load_seg(r, v, dn, s, delta, cont);
    float D = 0.f, C = 1.f;
#pragma unroll
    for (int i = SEG - 1; i >= 0; --i) { D = delta[i] + cont[i] * D; C *= cont[i]; }
    __shared__ float Ds[NT], Cs[NT];
    block_rscan(D, C, Ds, Cs, t);
    if (t == 0) aff[blockIdx.x] = make_float2(Ds[0], Cs[0]);
}

// Pass 2: reverse scan over chunk affines -> carry-in per chunk (single block)
__global__ __launch_bounds__(NT) void k_chunk_scan(const float2* __restrict__ aff,
                                                   float* __restrict__ carry, int nchunk) {
    const int t = threadIdx.x;
    const int per = nchunk / NT;  // 16
    const int s = t * per;
    float D = 0.f, C = 1.f;
    for (int i = per - 1; i >= 0; --i) { float2 a = aff[s + i]; D = a.x + a.y * D; C *= a.y; }
    __shared__ float Ds[NT], Cs[NT];
    block_rscan(D, C, Ds, Cs, t);
    float x = (t + 1 < NT) ? Ds[t + 1] : 0.f;  // value entering this thread's range from above
    for (int i = per - 1; i >= 0; --i) {
        int c = s + i;
        float2 a = aff[c];
        carry[c] = x;
        x = a.x + a.y * x;
    }
}

// Pass 3: final adv values + per-block (sum, sumsq)
__global__ __launch_bounds__(NT) void k_final(const float* __restrict__ r,
                                              const float* __restrict__ v,
                                              const int* __restrict__ dn,
                                              const float* __restrict__ carry,
                                              float* __restrict__ out,
                                              double2* __restrict__ partial) {
    const int t = threadIdx.x;
    const int chunk = blockIdx.x;
    const int s = chunk * CHUNK + t * SEG;
    float delta[SEG], cont[SEG];
    load_seg(r, v, dn, s, delta, cont);
    float D = 0.f, C = 1.f;
#pragma unroll
    for (int i = SEG - 1; i >= 0; --i) { D = delta[i] + cont[i] * D; C *= cont[i]; }
    __shared__ float Ds[NT], Cs[NT];
    block_rscan(D, C, Ds, Cs, t);
    float cc = carry[chunk];
    float x = (t + 1 < NT) ? (Ds[t + 1] + Cs[t + 1] * cc) : cc;
    float adv[SEG];
    float lsum = 0.f, lsq = 0.f;
#pragma unroll
    for (int i = SEG - 1; i >= 0; --i) {
        x = delta[i] + cont[i] * x;
        adv[i] = x;
        lsum += x;
        lsq += x * x;
    }
#pragma unroll
    for (int i = 0; i < 4; ++i)
        ((float4*)(out + s))[i] = make_float4(adv[4*i], adv[4*i+1], adv[4*i+2], adv[4*i+3]);

    // deterministic block reduction into doubles
    double dsum = (double)lsum, dsq = (double)lsq;
    for (int off = 32; off > 0; off >>= 1) {
        dsum += __shfl_down(dsum, off, 64);
        dsq  += __shfl_down(dsq,  off, 64);
    }
    __shared__ double Ssum[NT / 64], Ssq[NT / 64];
    const int wave = t >> 6, lane = t & 63;
    if (lane == 0) { Ssum[wave] = dsum; Ssq[wave] = dsq; }
    __syncthreads();
    if (t == 0) {
        double a = 0.0, b = 0.0;
        for (int w = 0; w < NT / 64; ++w) { a += Ssum[w]; b += Ssq[w]; }
        partial[chunk] = make_double2(a, b);
    }
}

// Pass 4: reduce partials -> mean, 1/(std+eps)
__global__ __launch_bounds__(NT) void k_stats(const double2* __restrict__ partial,
                                              int nchunk, float2* __restrict__ meanstd,
                                              long long T) {
    const int t = threadIdx.x;
    double a = 0.0, b = 0.0;
    for (int i = t; i < nchunk; i += NT) { double2 p = partial[i]; a += p.x; b += p.y; }
    for (int off = 32; off > 0; off >>= 1) {
        a += __shfl_down(a, off, 64);
        b += __shfl_down(b, off, 64);
    }
    __shared__ double Sa[NT / 64], Sb[NT / 64];
    const int wave = t >> 6, lane = t & 63;
    if (lane == 0) { Sa[wave] = a; Sb[wave] = b; }
    __syncthreads();
    if (t == 0) {
        double s = 0.0, q = 0.0;
        for (int w = 0; w < NT / 64; ++w) { s += Sa[w]; q += Sb[w]; }
        double mean = s / (double)T;
        double var = q / (double)T - mean * mean;
        double sd = sqrt(var > 0.0 ? var : 0.0);
        meanstd[0] = make_float2((float)mean, (float)(1.0 / (sd + (double)EPS_F)));
    }
}

// Pass 5: standardize in place
__global__ __launch_bounds__(NT) void k_norm(float* __restrict__ out,
                                             const float2* __restrict__ meanstd,
                                             int n4) {
    const float2 ms = *meanstd;
    float4* o4 = (float4*)out;
    int i = blockIdx.x * blockDim.x + threadIdx.x;
    const int stride = gridDim.x * blockDim.x;
    for (; i < n4; i += stride) {
        float4 v = o4[i];
        v.x = (v.x - ms.x) * ms.y;
        v.y = (v.y - ms.x) * ms.y;
        v.z = (v.z - ms.x) * ms.y;
        v.w = (v.w - ms.x) * ms.y;
        o4[i] = v;
    }
}

extern "C" void kernel_launch(void* const* d_in, const int* in_sizes, int n_in,
                              void* d_out, int out_size, void* d_ws, size_t ws_size,
                              hipStream_t stream) {
    const float* rewards = (const float*)d_in[0];
    const float* v_pred  = (const float*)d_in[1];
    const int*   dones   = (const int*)d_in[2];
    float* out = (float*)d_out;
    const long long T = in_sizes[0];           // 16777216
    const int nchunk = (int)(T / CHUNK);       // 4096 (T divisible by 4096)

    char* ws = (char*)d_ws;
    float2*  aff     = (float2*)ws;                                       // nchunk*8 B
    float*   carry   = (float*)(ws + (size_t)nchunk * 8);                 // nchunk*4 B
    double2* partial = (double2*)(ws + (size_t)nchunk * 12);              // nchunk*16 B (offset 49152, 16B aligned)
    float2*  meanstd = (float2*)(ws + (size_t)nchunk * 12 + (size_t)nchunk * 16);

    hipLaunchKernelGGL(k_chunk_affine, dim3(nchunk), dim3(NT), 0, stream,
                       rewards, v_pred, dones, aff);
    hipLaunchKernelGGL(k_chunk_scan, dim3(1), dim3(NT), 0, stream, aff, carry, nchunk);
    hipLaunchKernelGGL(k_final, dim3(nchunk), dim3(NT), 0, stream,
                       rewards, v_pred, dones, carry, out, partial);
    hipLaunchKernelGGL(k_stats, dim3(1), dim3(NT), 0, stream, partial, nchunk, meanstd, T);
    hipLaunchKernelGGL(k_norm, dim3(2048), dim3(NT), 0, stream, out, meanstd, (int)(T / 4));
}